// Round 17
// baseline (219.149 us; speedup 1.0000x reference)
//
#include <hip/hip_runtime.h>

#define QLEN 1024
#define KLEN 2048   // MLEN + QLEN

typedef float f32x2 __attribute__((ext_vector_type(2)));
typedef float f32x4 __attribute__((ext_vector_type(4)));

static constexpr float INV2PI = 0.15915494309189535f;
static constexpr float TGUARD = 3e-5f;

// packed fp32 VOP3P ops (r7: assemble + compute correctly on gfx950)
static __device__ __forceinline__ f32x2 pk_add(f32x2 a, f32x2 b) {
    f32x2 d; asm("v_pk_add_f32 %0, %1, %2" : "=v"(d) : "v"(a), "v"(b)); return d;
}
static __device__ __forceinline__ f32x2 pk_mul(f32x2 a, f32x2 b) {
    f32x2 d; asm("v_pk_mul_f32 %0, %1, %2" : "=v"(d) : "v"(a), "v"(b)); return d;
}
static __device__ __forceinline__ f32x2 pk_fma(f32x2 a, f32x2 b, f32x2 c) {
    f32x2 d; asm("v_pk_fma_f32 %0, %1, %2, %3" : "=v"(d) : "v"(a), "v"(b), "v"(c)); return d;
}

// ---------------------------------------------------------------------------
// Fused projection + sincos precompute. Q-side SIGN-FLIPPED (-p, -sin, cos)
// (r7-verified): main loop then needs no negations —
//   u~ = (-pq) + pk = -(pq-pk);  n~ = cq*sk + (-sq)*ck = -sin(R(pq-pk))
// and signs cancel per-factor in g = prod(n~)/prod(u~); final fabs anyway.
// Layout per token: float4 index = (tok*12 + part*4 + c)*32 + bh
// ---------------------------------------------------------------------------
__global__ __launch_bounds__(256) void fa_proj_kernel(
    const float* __restrict__ h, const float* __restrict__ mems,
    const float* __restrict__ Wq, const float* __restrict__ Wk,
    const float* __restrict__ paramR,
    float* __restrict__ Rq3, float* __restrict__ Rk3)
{
    __shared__ float inT[128 * 36];
    const int tid  = threadIdx.x;
    const bool isQ = blockIdx.x < 128;
    const int  blk = isQ ? blockIdx.x : blockIdx.x - 128;
    const int row0 = blk * 32;
    const float* W   = isQ ? Wq : Wk;
    float*      out3 = isQ ? Rq3 : Rk3;
    const float sgn  = isQ ? -1.0f : 1.0f;

    for (int idx = tid; idx < 32 * 128; idx += 256) {
        int r = idx >> 7;
        int e = idx & 127;
        int grow = row0 + r;
        float v;
        if (isQ)               v = h[(size_t)grow * 128 + e];
        else if (grow < 4096)  v = mems[(size_t)grow * 128 + e];
        else                   v = h[(size_t)(grow - 4096) * 128 + e];
        inT[e * 36 + r] = v;
    }
    __syncthreads();

    const int col  = tid & 127;
    const int half = tid >> 7;

    float acc[16];
#pragma unroll
    for (int j = 0; j < 16; ++j) acc[j] = 0.0f;

#pragma unroll 2
    for (int e = 0; e < 128; ++e) {
        float w = W[e * 128 + col];
        const float4* ap = reinterpret_cast<const float4*>(&inT[e * 36 + half * 16]);
        float4 a0 = ap[0], a1 = ap[1], a2 = ap[2], a3 = ap[3];
        float av[16];
        av[0]=a0.x; av[1]=a0.y; av[2]=a0.z; av[3]=a0.w;
        av[4]=a1.x; av[5]=a1.y; av[6]=a1.z; av[7]=a1.w;
        av[8]=a2.x; av[9]=a2.y; av[10]=a2.z; av[11]=a2.w;
        av[12]=a3.x; av[13]=a3.y; av[14]=a3.z; av[15]=a3.w;
#pragma unroll
        for (int j = 0; j < 16; ++j) acc[j] = fmaf(av[j], w, acc[j]);
    }

    const int hh = col >> 4;
    const int d  = col & 15;
    const float Rrev = paramR[hh] * INV2PI;

#pragma unroll
    for (int j = 0; j < 16; ++j) {
        int r   = row0 + half * 16 + j;
        int tok = r >> 2;
        int b   = r & 3;
        int bh  = b * 8 + hh;
        float p = acc[j];
        float s = __builtin_amdgcn_sinf(Rrev * p);
        float c = __builtin_amdgcn_cosf(Rrev * p);
        int base = ((tok * 12 + (d >> 2)) * 32 + bh) * 4 + (d & 3);
        out3[base]        = sgn * p;
        out3[base + 512]  = sgn * s;
        out3[base + 1024] = c;
    }
}

#define SHUF_LO(v) __builtin_shufflevector((v), (v), 0, 1)
#define SHUF_HI(v) __builtin_shufflevector((v), (v), 2, 3)

// ---------------------------------------------------------------------------
// Main kernel — r15 structure (199 us), math stream moved to packed fp32.
// Cadence finding (r16): wave64 VALU issues ~4 cyc/inst; r15 was AT the
// issue roofline for its ~105-inst/token stream (VALUBusy 87%). v_pk_*_f32
// does 2 fp32 ops per issue slot -> the 72 elementwise ops/token become
// 36 pk slots. Clean test: TQ=2, loose (256,2) budget (no r7 spill trap),
// unchanged grid/staging/barriers.
// ---------------------------------------------------------------------------
__global__ __launch_bounds__(256, 2) void fa_fourier_main(
    const float* __restrict__ Rq3, const float* __restrict__ Rk3,
    const float* __restrict__ paramR, float* __restrict__ out)
{
    __shared__ f32x4 kbuf[2][768];    // 2 x (2 tok x 12 x 32) float4 = 24576 B

    const int tid   = threadIdx.x;
    const int wv    = tid >> 6;
    const int l     = tid & 63;
    const int dhalf = l >> 5;          // which 8 of the 16 d's
    const int bh    = l & 31;
    const int bid   = blockIdx.x;
    const int ch    = bid & 15;        // k-chunk (128 tokens), XCD-pinned
    const int x     = bid >> 4;        // q-block 0..127
    const int k0    = ch * 128;
    const int qb    = x * 8 + wv * 2;

    const float R = paramR[bh & 7];

    // q-state: 2 q x {p~,s~,c} x 4 f32x2 (own 8 d's) = 48 floats
    f32x2 qp[2][4], qs[2][4], qc[2][4];
    {
        const f32x4* qsrc = reinterpret_cast<const f32x4*>(Rq3);
#pragma unroll
        for (int q = 0; q < 2; ++q) {
            size_t tb = (size_t)(qb + q) * 12;
#pragma unroll
            for (int j = 0; j < 2; ++j) {
                f32x4 pv = qsrc[(tb + 0 + dhalf * 2 + j) * 32 + bh];
                f32x4 sv = qsrc[(tb + 4 + dhalf * 2 + j) * 32 + bh];
                f32x4 cv = qsrc[(tb + 8 + dhalf * 2 + j) * 32 + bh];
                qp[q][2*j] = SHUF_LO(pv);  qp[q][2*j+1] = SHUF_HI(pv);
                qs[q][2*j] = SHUF_LO(sv);  qs[q][2*j+1] = SHUF_HI(sv);
                qc[q][2*j] = SHUF_LO(cv);  qc[q][2*j+1] = SHUF_HI(cv);
            }
        }
    }

    const f32x4* ksrc = reinterpret_cast<const f32x4*>(Rk3);

    // this lane stores q-row qb+dhalf
    float* outRow = out + ((size_t)(qb + dhalf) * KLEN + k0) * 32 + bh;

    // stage 2-token window w into buffer parity (3 x 16B per thread)
    auto stage = [&](int w, int parity) {
        size_t gbase = (size_t)(k0 + w * 2) * 384;
#pragma unroll
        for (int i = 0; i < 3; ++i) {
            int fi = i * 256 + tid;
            __builtin_amdgcn_global_load_lds(
                (const __attribute__((address_space(1))) void*)(ksrc + gbase + fi),
                (__attribute__((address_space(3))) void*)(&kbuf[parity][fi]),
                16, 0, 0);
        }
    };

    stage(0, 0);
    __builtin_amdgcn_sched_barrier(0);
    asm volatile("s_waitcnt vmcnt(0)\n\ts_barrier");
    __builtin_amdgcn_sched_barrier(0);

    for (int w = 0; w < 64; ++w) {
        if (w < 63) stage(w + 1, (w + 1) & 1);
        const f32x4* kb = kbuf[w & 1] + bh;

#pragma unroll
        for (int t = 0; t < 2; ++t) {
            // k half-state: 6 ds_read_b128, split to f32x2 sub-registers (free)
            f32x4 kp4a = kb[(t * 12 + 0 + dhalf * 2 + 0) * 32];
            f32x4 kp4b = kb[(t * 12 + 0 + dhalf * 2 + 1) * 32];
            f32x4 ks4a = kb[(t * 12 + 4 + dhalf * 2 + 0) * 32];
            f32x4 ks4b = kb[(t * 12 + 4 + dhalf * 2 + 1) * 32];
            f32x4 kc4a = kb[(t * 12 + 8 + dhalf * 2 + 0) * 32];
            f32x4 kc4b = kb[(t * 12 + 8 + dhalf * 2 + 1) * 32];
            f32x2 kp[4] = {SHUF_LO(kp4a), SHUF_HI(kp4a), SHUF_LO(kp4b), SHUF_HI(kp4b)};
            f32x2 ks[4] = {SHUF_LO(ks4a), SHUF_HI(ks4a), SHUF_LO(ks4b), SHUF_HI(ks4b)};
            f32x2 kc[4] = {SHUF_LO(kc4a), SHUF_HI(kc4a), SHUF_LO(kc4b), SHUF_HI(kc4b)};

            float g[2];
#pragma unroll
            for (int q = 0; q < 2; ++q) {
                // u~ = q~p + kp ; n~ = qc*ks + q~s*kc   (all packed, no negs)
                f32x2 u0 = pk_add(qp[q][0], kp[0]);
                f32x2 u1 = pk_add(qp[q][1], kp[1]);
                f32x2 u2 = pk_add(qp[q][2], kp[2]);
                f32x2 u3 = pk_add(qp[q][3], kp[3]);
                f32x2 t0 = pk_mul(qs[q][0], kc[0]);
                f32x2 t1 = pk_mul(qs[q][1], kc[1]);
                f32x2 t2 = pk_mul(qs[q][2], kc[2]);
                f32x2 t3 = pk_mul(qs[q][3], kc[3]);
                f32x2 n0 = pk_fma(qc[q][0], ks[0], t0);
                f32x2 n1 = pk_fma(qc[q][1], ks[1], t1);
                f32x2 n2 = pk_fma(qc[q][2], ks[2], t2);
                f32x2 n3 = pk_fma(qc[q][3], ks[3], t3);
                f32x2 uA = pk_mul(u0, u1);
                f32x2 uB = pk_mul(u2, u3);
                f32x2 uQ = pk_mul(uA, uB);
                f32x2 nA = pk_mul(n0, n1);
                f32x2 nB = pk_mul(n2, n3);
                f32x2 nQ = pk_mul(nA, nB);
                float uh = uQ[0] * uQ[1];
                float nh = nQ[0] * nQ[1];
                // guard min-tree (scalar; v_min3-fusable, abs as src modifier)
                float ma = fminf(fminf(fabsf(u0[0]), fabsf(u0[1])), fabsf(u1[0]));
                float mb = fminf(fminf(fabsf(u1[1]), fabsf(u2[0])), fabsf(u2[1]));
                float mc = fminf(fminf(fabsf(u3[0]), fabsf(u3[1])), ma);
                float mn = fminf(mb, mc);
                if (__builtin_expect(mn < TGUARD, 0)) {
                    // lane-local guarded recompute (rare); flipped-sign
                    // semantics: factor (-n)/(-u) == n/u; guarded d -> R/1.
                    float pu = 1.0f, pn = 1.0f;
#pragma unroll
                    for (int j = 0; j < 4; ++j) {
#pragma unroll
                        for (int e = 0; e < 2; ++e) {
                            float u = qp[q][j][e] + kp[j][e];
                            float n = fmaf(qc[q][j][e], ks[j][e],
                                           qs[q][j][e] * kc[j][e]);
                            if (fabsf(u) < TGUARD) {
                                float ru = R * u;
                                n = R * fmaf(-ru * ru, 0.16666667f, 1.0f);
                                u = 1.0f;
                            }
                            pu *= u; pn *= n;
                        }
                    }
                    if (fabsf(pu) < 1e-30f) pu = (pu < 0.0f) ? -1e-30f : 1e-30f;
                    uh = pu; nh = pn;
                }
                g[q] = nh * __builtin_amdgcn_rcpf(uh);
            }

            // pair exchange: dhalf0 stores q0, dhalf1 stores q1
            float send = dhalf ? g[0] : g[1];
            float recv = __shfl_xor(send, 32, 64);
            float mine = dhalf ? g[1] : g[0];

            __builtin_nontemporal_store(fabsf(mine * recv),
                                        outRow + (size_t)(w * 2 + t) * 32);
        }

        if (w < 63) {
            // counted-vmcnt barrier: queue tail = [3 loads][2 stores] ->
            // vmcnt(2) proves next window's staging landed; stores fly on.
            __builtin_amdgcn_sched_barrier(0);
            asm volatile("s_waitcnt vmcnt(2)\n\ts_barrier");
            __builtin_amdgcn_sched_barrier(0);
        }
    }
}

extern "C" void kernel_launch(void* const* d_in, const int* in_sizes, int n_in,
                              void* d_out, int out_size, void* d_ws, size_t ws_size,
                              hipStream_t stream)
{
    const float* h    = (const float*)d_in[0];   // [1024,4,128]
    const float* mems = (const float*)d_in[1];   // [1024,4,128]
    const float* Wq   = (const float*)d_in[2];   // [128,128]
    const float* Wk   = (const float*)d_in[3];   // [128,128]
    const float* R    = (const float*)d_in[4];   // [8]
    float* out = (float*)d_out;                  // [1024,2048,4,8] fp32

    float* Rq3 = (float*)d_ws;                   // 1024*1536 floats (6 MB)
    float* Rk3 = Rq3 + (size_t)1024 * 1536;      // 2048*1536 floats (12 MB)

    fa_proj_kernel<<<dim3(384), 256, 0, stream>>>(h, mems, Wq, Wk, R, Rq3, Rk3);

    // 128 q-blocks x 16 k-chunks = 2048 blocks; bid&15 = chunk (XCD-clean)
    fa_fourier_main<<<dim3(2048), 256, 0, stream>>>(Rq3, Rk3, R, out);
}

// Round 18
// 218.939 us; speedup vs baseline: 1.0010x; 1.0010x over previous
//
#include <hip/hip_runtime.h>

#define QLEN 1024
#define KLEN 2048   // MLEN + QLEN

typedef float f32x2 __attribute__((ext_vector_type(2)));
typedef float f32x4 __attribute__((ext_vector_type(4)));

static constexpr float INV2PI = 0.15915494309189535f;
static constexpr float TGUARD = 3e-5f;

// packed fp32 VOP3P ops (r7: assemble + compute correctly on gfx950)
static __device__ __forceinline__ f32x2 pk_add(f32x2 a, f32x2 b) {
    f32x2 d; asm("v_pk_add_f32 %0, %1, %2" : "=v"(d) : "v"(a), "v"(b)); return d;
}
static __device__ __forceinline__ f32x2 pk_mul(f32x2 a, f32x2 b) {
    f32x2 d; asm("v_pk_mul_f32 %0, %1, %2" : "=v"(d) : "v"(a), "v"(b)); return d;
}
static __device__ __forceinline__ f32x2 pk_fma(f32x2 a, f32x2 b, f32x2 c) {
    f32x2 d; asm("v_pk_fma_f32 %0, %1, %2, %3" : "=v"(d) : "v"(a), "v"(b), "v"(c)); return d;
}

// ---------------------------------------------------------------------------
// Fused projection + sincos precompute. Q-side SIGN-FLIPPED (-p, -sin, cos)
// (r7-verified): main loop then needs no negations —
//   u~ = (-pq) + pk = -(pq-pk);  n~ = cq*sk + (-sq)*ck = -sin(R(pq-pk))
// and signs cancel per-factor in g = prod(n~)/prod(u~); final fabs anyway.
// Layout per token: float4 index = (tok*12 + part*4 + c)*32 + bh
// ---------------------------------------------------------------------------
__global__ __launch_bounds__(256) void fa_proj_kernel(
    const float* __restrict__ h, const float* __restrict__ mems,
    const float* __restrict__ Wq, const float* __restrict__ Wk,
    const float* __restrict__ paramR,
    float* __restrict__ Rq3, float* __restrict__ Rk3)
{
    __shared__ float inT[128 * 36];
    const int tid  = threadIdx.x;
    const bool isQ = blockIdx.x < 128;
    const int  blk = isQ ? blockIdx.x : blockIdx.x - 128;
    const int row0 = blk * 32;
    const float* W   = isQ ? Wq : Wk;
    float*      out3 = isQ ? Rq3 : Rk3;
    const float sgn  = isQ ? -1.0f : 1.0f;

    for (int idx = tid; idx < 32 * 128; idx += 256) {
        int r = idx >> 7;
        int e = idx & 127;
        int grow = row0 + r;
        float v;
        if (isQ)               v = h[(size_t)grow * 128 + e];
        else if (grow < 4096)  v = mems[(size_t)grow * 128 + e];
        else                   v = h[(size_t)(grow - 4096) * 128 + e];
        inT[e * 36 + r] = v;
    }
    __syncthreads();

    const int col  = tid & 127;
    const int half = tid >> 7;

    float acc[16];
#pragma unroll
    for (int j = 0; j < 16; ++j) acc[j] = 0.0f;

#pragma unroll 2
    for (int e = 0; e < 128; ++e) {
        float w = W[e * 128 + col];
        const float4* ap = reinterpret_cast<const float4*>(&inT[e * 36 + half * 16]);
        float4 a0 = ap[0], a1 = ap[1], a2 = ap[2], a3 = ap[3];
        float av[16];
        av[0]=a0.x; av[1]=a0.y; av[2]=a0.z; av[3]=a0.w;
        av[4]=a1.x; av[5]=a1.y; av[6]=a1.z; av[7]=a1.w;
        av[8]=a2.x; av[9]=a2.y; av[10]=a2.z; av[11]=a2.w;
        av[12]=a3.x; av[13]=a3.y; av[14]=a3.z; av[15]=a3.w;
#pragma unroll
        for (int j = 0; j < 16; ++j) acc[j] = fmaf(av[j], w, acc[j]);
    }

    const int hh = col >> 4;
    const int d  = col & 15;
    const float Rrev = paramR[hh] * INV2PI;

#pragma unroll
    for (int j = 0; j < 16; ++j) {
        int r   = row0 + half * 16 + j;
        int tok = r >> 2;
        int b   = r & 3;
        int bh  = b * 8 + hh;
        float p = acc[j];
        float s = __builtin_amdgcn_sinf(Rrev * p);
        float c = __builtin_amdgcn_cosf(Rrev * p);
        int base = ((tok * 12 + (d >> 2)) * 32 + bh) * 4 + (d & 3);
        out3[base]        = sgn * p;
        out3[base + 512]  = sgn * s;
        out3[base + 1024] = c;
    }
}

#define SHUF_LO(v) __builtin_shufflevector((v), (v), 0, 1)
#define SHUF_HI(v) __builtin_shufflevector((v), (v), 2, 3)

// ---------------------------------------------------------------------------
// Main kernel — r15 structure (199 us), math stream moved to packed fp32.
// Cadence finding (r16): wave64 VALU issues ~4 cyc/inst; r15 was AT the
// issue roofline for its ~105-inst/token stream (VALUBusy 87%). v_pk_*_f32
// does 2 fp32 ops per issue slot -> the 72 elementwise ops/token become
// 36 pk slots. Clean test: TQ=2, loose (256,2) budget (no r7 spill trap),
// unchanged grid/staging/barriers.
// ---------------------------------------------------------------------------
__global__ __launch_bounds__(256, 2) void fa_fourier_main(
    const float* __restrict__ Rq3, const float* __restrict__ Rk3,
    const float* __restrict__ paramR, float* __restrict__ out)
{
    __shared__ f32x4 kbuf[2][768];    // 2 x (2 tok x 12 x 32) float4 = 24576 B

    const int tid   = threadIdx.x;
    const int wv    = tid >> 6;
    const int l     = tid & 63;
    const int dhalf = l >> 5;          // which 8 of the 16 d's
    const int bh    = l & 31;
    const int bid   = blockIdx.x;
    const int ch    = bid & 15;        // k-chunk (128 tokens), XCD-pinned
    const int x     = bid >> 4;        // q-block 0..127
    const int k0    = ch * 128;
    const int qb    = x * 8 + wv * 2;

    const float R = paramR[bh & 7];

    // q-state: 2 q x {p~,s~,c} x 4 f32x2 (own 8 d's) = 48 floats
    f32x2 qp[2][4], qs[2][4], qc[2][4];
    {
        const f32x4* qsrc = reinterpret_cast<const f32x4*>(Rq3);
#pragma unroll
        for (int q = 0; q < 2; ++q) {
            size_t tb = (size_t)(qb + q) * 12;
#pragma unroll
            for (int j = 0; j < 2; ++j) {
                f32x4 pv = qsrc[(tb + 0 + dhalf * 2 + j) * 32 + bh];
                f32x4 sv = qsrc[(tb + 4 + dhalf * 2 + j) * 32 + bh];
                f32x4 cv = qsrc[(tb + 8 + dhalf * 2 + j) * 32 + bh];
                qp[q][2*j] = SHUF_LO(pv);  qp[q][2*j+1] = SHUF_HI(pv);
                qs[q][2*j] = SHUF_LO(sv);  qs[q][2*j+1] = SHUF_HI(sv);
                qc[q][2*j] = SHUF_LO(cv);  qc[q][2*j+1] = SHUF_HI(cv);
            }
        }
    }

    const f32x4* ksrc = reinterpret_cast<const f32x4*>(Rk3);

    // this lane stores q-row qb+dhalf
    float* outRow = out + ((size_t)(qb + dhalf) * KLEN + k0) * 32 + bh;

    // stage 2-token window w into buffer parity (3 x 16B per thread)
    auto stage = [&](int w, int parity) {
        size_t gbase = (size_t)(k0 + w * 2) * 384;
#pragma unroll
        for (int i = 0; i < 3; ++i) {
            int fi = i * 256 + tid;
            __builtin_amdgcn_global_load_lds(
                (const __attribute__((address_space(1))) void*)(ksrc + gbase + fi),
                (__attribute__((address_space(3))) void*)(&kbuf[parity][fi]),
                16, 0, 0);
        }
    };

    stage(0, 0);
    __builtin_amdgcn_sched_barrier(0);
    asm volatile("s_waitcnt vmcnt(0)\n\ts_barrier");
    __builtin_amdgcn_sched_barrier(0);

    for (int w = 0; w < 64; ++w) {
        if (w < 63) stage(w + 1, (w + 1) & 1);
        const f32x4* kb = kbuf[w & 1] + bh;

#pragma unroll
        for (int t = 0; t < 2; ++t) {
            // k half-state: 6 ds_read_b128, split to f32x2 sub-registers (free)
            f32x4 kp4a = kb[(t * 12 + 0 + dhalf * 2 + 0) * 32];
            f32x4 kp4b = kb[(t * 12 + 0 + dhalf * 2 + 1) * 32];
            f32x4 ks4a = kb[(t * 12 + 4 + dhalf * 2 + 0) * 32];
            f32x4 ks4b = kb[(t * 12 + 4 + dhalf * 2 + 1) * 32];
            f32x4 kc4a = kb[(t * 12 + 8 + dhalf * 2 + 0) * 32];
            f32x4 kc4b = kb[(t * 12 + 8 + dhalf * 2 + 1) * 32];
            f32x2 kp[4] = {SHUF_LO(kp4a), SHUF_HI(kp4a), SHUF_LO(kp4b), SHUF_HI(kp4b)};
            f32x2 ks[4] = {SHUF_LO(ks4a), SHUF_HI(ks4a), SHUF_LO(ks4b), SHUF_HI(ks4b)};
            f32x2 kc[4] = {SHUF_LO(kc4a), SHUF_HI(kc4a), SHUF_LO(kc4b), SHUF_HI(kc4b)};

            float g[2];
#pragma unroll
            for (int q = 0; q < 2; ++q) {
                // u~ = q~p + kp ; n~ = qc*ks + q~s*kc   (all packed, no negs)
                f32x2 u0 = pk_add(qp[q][0], kp[0]);
                f32x2 u1 = pk_add(qp[q][1], kp[1]);
                f32x2 u2 = pk_add(qp[q][2], kp[2]);
                f32x2 u3 = pk_add(qp[q][3], kp[3]);
                f32x2 t0 = pk_mul(qs[q][0], kc[0]);
                f32x2 t1 = pk_mul(qs[q][1], kc[1]);
                f32x2 t2 = pk_mul(qs[q][2], kc[2]);
                f32x2 t3 = pk_mul(qs[q][3], kc[3]);
                f32x2 n0 = pk_fma(qc[q][0], ks[0], t0);
                f32x2 n1 = pk_fma(qc[q][1], ks[1], t1);
                f32x2 n2 = pk_fma(qc[q][2], ks[2], t2);
                f32x2 n3 = pk_fma(qc[q][3], ks[3], t3);
                f32x2 uA = pk_mul(u0, u1);
                f32x2 uB = pk_mul(u2, u3);
                f32x2 uQ = pk_mul(uA, uB);
                f32x2 nA = pk_mul(n0, n1);
                f32x2 nB = pk_mul(n2, n3);
                f32x2 nQ = pk_mul(nA, nB);
                float uh = uQ[0] * uQ[1];
                float nh = nQ[0] * nQ[1];
                // guard min-tree (scalar; v_min3-fusable, abs as src modifier)
                float ma = fminf(fminf(fabsf(u0[0]), fabsf(u0[1])), fabsf(u1[0]));
                float mb = fminf(fminf(fabsf(u1[1]), fabsf(u2[0])), fabsf(u2[1]));
                float mc = fminf(fminf(fabsf(u3[0]), fabsf(u3[1])), ma);
                float mn = fminf(mb, mc);
                if (__builtin_expect(mn < TGUARD, 0)) {
                    // lane-local guarded recompute (rare); flipped-sign
                    // semantics: factor (-n)/(-u) == n/u; guarded d -> R/1.
                    float pu = 1.0f, pn = 1.0f;
#pragma unroll
                    for (int j = 0; j < 4; ++j) {
#pragma unroll
                        for (int e = 0; e < 2; ++e) {
                            float u = qp[q][j][e] + kp[j][e];
                            float n = fmaf(qc[q][j][e], ks[j][e],
                                           qs[q][j][e] * kc[j][e]);
                            if (fabsf(u) < TGUARD) {
                                float ru = R * u;
                                n = R * fmaf(-ru * ru, 0.16666667f, 1.0f);
                                u = 1.0f;
                            }
                            pu *= u; pn *= n;
                        }
                    }
                    if (fabsf(pu) < 1e-30f) pu = (pu < 0.0f) ? -1e-30f : 1e-30f;
                    uh = pu; nh = pn;
                }
                g[q] = nh * __builtin_amdgcn_rcpf(uh);
            }

            // pair exchange: dhalf0 stores q0, dhalf1 stores q1
            float send = dhalf ? g[0] : g[1];
            float recv = __shfl_xor(send, 32, 64);
            float mine = dhalf ? g[1] : g[0];

            __builtin_nontemporal_store(fabsf(mine * recv),
                                        outRow + (size_t)(w * 2 + t) * 32);
        }

        if (w < 63) {
            // counted-vmcnt barrier: queue tail = [3 loads][2 stores] ->
            // vmcnt(2) proves next window's staging landed; stores fly on.
            __builtin_amdgcn_sched_barrier(0);
            asm volatile("s_waitcnt vmcnt(2)\n\ts_barrier");
            __builtin_amdgcn_sched_barrier(0);
        }
    }
}

extern "C" void kernel_launch(void* const* d_in, const int* in_sizes, int n_in,
                              void* d_out, int out_size, void* d_ws, size_t ws_size,
                              hipStream_t stream)
{
    const float* h    = (const float*)d_in[0];   // [1024,4,128]
    const float* mems = (const float*)d_in[1];   // [1024,4,128]
    const float* Wq   = (const float*)d_in[2];   // [128,128]
    const float* Wk   = (const float*)d_in[3];   // [128,128]
    const float* R    = (const float*)d_in[4];   // [8]
    float* out = (float*)d_out;                  // [1024,2048,4,8] fp32

    float* Rq3 = (float*)d_ws;                   // 1024*1536 floats (6 MB)
    float* Rk3 = Rq3 + (size_t)1024 * 1536;      // 2048*1536 floats (12 MB)

    fa_proj_kernel<<<dim3(384), 256, 0, stream>>>(h, mems, Wq, Wk, R, Rq3, Rk3);

    // 128 q-blocks x 16 k-chunks = 2048 blocks; bid&15 = chunk (XCD-clean)
    fa_fourier_main<<<dim3(2048), 256, 0, stream>>>(Rq3, Rk3, R, out);
}